// Round 2
// 969.699 us; speedup vs baseline: 1.1537x; 1.1537x over previous
//
#include <hip/hip_runtime.h>
#include <stdint.h>

typedef unsigned short u16;
typedef unsigned char  u8;
typedef unsigned int   u32;
typedef __attribute__((ext_vector_type(8))) short  short8;
typedef __attribute__((ext_vector_type(4))) float  floatx4;

#define Bz   16
#define Mm   1024
#define Nn   1024
#define Dd   1024
#define HIDh 512
#define INV_SQRT_D 0.03125f
#define NEGINF (-1.0e9f)
#define BMDc  ((size_t)Bz * Mm * Dd)
#define sMDc  ((long)Mm * Dd)

__device__ __forceinline__ float bf2f(u16 h) {
    union { u32 u; float f; } c; c.u = ((u32)h) << 16; return c.f;
}
__device__ __forceinline__ u16 f2bf(float f) {
    union { float f; u32 u; } c; c.f = f;
    u32 u = c.u;
    return (u16)((u + 0x7FFFu + ((u >> 16) & 1u)) >> 16);
}
// async global->LDS, 16B/lane; lds ptr wave-uniform (HW adds lane*16)
__device__ __forceinline__ void g2lds16(const u16* g, u16* l) {
    __builtin_amdgcn_global_load_lds((const __attribute__((address_space(1))) void*)g,
                                     (__attribute__((address_space(3))) void*)l, 16, 0, 0);
}

__device__ __forceinline__ float waveSum(float v) {
#pragma unroll
    for (int o = 32; o > 0; o >>= 1) v += __shfl_xor(v, o);
    return v;
}
__device__ __forceinline__ float waveMax(float v) {
#pragma unroll
    for (int o = 32; o > 0; o >>= 1) v = fmaxf(v, __shfl_xor(v, o));
    return v;
}

// ===================== 256x256 8-phase GEMM:  C = A * B^T  (bf16 in, fp32 acc) =====================
// Schedule (per K-tile t, BK=64, buf cb=t&1; 4 phases, quadrant order (m0-3,n0-1)(m0-3,n2-3)(m4-7,n2-3)(m4-7,n0-1)):
//   reads retire:  ph0: A-lo + B-lo;  ph1: B-hi;  ph2: A-hi;  ph3: none
//   stages (1 half-tile = 2 gload_lds/thread):  ph0: B-lo(t+1) -> buf^1 ;  ph1: A-lo(t+2) -> buf ;
//                                               ph2: B-hi(t+2) -> buf  ;  ph3: A-hi(t+2) -> buf
//   every stage targets a region retired one barrier earlier => race-free.
//   vmcnt(6) once per tile boundary (3 half-tiles = 6 loads stay in flight); never 0 until last tile.
// LDS swizzle: chunk' = chunk ^ (row&7) (16B granule) — applied via linear gload dest +
//   inverse-swizzled GLOBAL source column + swizzled ds_read address (both-sides pattern).
template <bool OUT_FP32, bool BIAS, bool TRANSC>
__global__ __launch_bounds__(512, 2) void gemm256(
    const u16* __restrict__ A, const u16* __restrict__ Bm,
    const float* __restrict__ bias, void* __restrict__ Cv,
    int K, int ldc, long sA, long sB, long sC)
{
    __shared__ __align__(16) u16 lds[2][2][256 * 64];   // [buf][A=0/B=1][row*64+col], 128 KiB
    const int tid  = threadIdx.x;
    const int lane = tid & 63;
    const int wv   = tid >> 6;          // 0..7
    const int wr   = wv >> 2;           // M half  (0..1)
    const int wc   = wv & 3;            // N quarter (0..3)
    const int fr   = lane & 15, fq = lane >> 4;

    // XCD-chunked bijective block swizzle (all grids here have nwg==256, %8==0)
    const int gX = gridDim.x, gY = gridDim.y;
    int bid = blockIdx.x + gX * (blockIdx.y + gY * blockIdx.z);
    const int nwg = gX * gY * gridDim.z;
    int wg = (bid & 7) * (nwg >> 3) + (bid >> 3);
    const int bx = wg % gX; wg /= gX;
    const int by = wg % gY;
    const int bz = wg / gY;

    const long tileM = (long)bx * 256, tileN = (long)by * 256;
    A  += (long)bz * sA;
    Bm += (long)bz * sB;
    const int T = K >> 6;               // K-tiles; K=1024 -> 16 (code assumes T>=2)

    floatx4 acc[8][4];
#pragma unroll
    for (int i = 0; i < 8; ++i)
#pragma unroll
        for (int j = 0; j < 4; ++j) acc[i][j] = (floatx4){0.f, 0.f, 0.f, 0.f};

    const int lrow = lane >> 3;                    // 0..7 within 8-row block
    const int scol = ((lane & 7) ^ lrow) << 3;     // inverse-swizzled source col (u16 units)
    const int sw   = fr & 7;
    const int kc0  = ((fq ^ sw) << 3);             // swizzled ds_read col for kk=0
    const int kc1  = (((4 + fq) ^ sw) << 3);       // kk=1

    // stage one half-tile: side 0=A rows {wrr*128+hh*64+0..63}; side 1=B rows {blk*64+hh*32+0..31}
    auto stage = [&](int tt, int side, int hh, int bb) {
#pragma unroll
        for (int i = 0; i < 2; ++i) {
            const int j = i * 8 + wv;
            const int prow = side ? (((j >> 2) << 6) + (hh << 5) + ((j & 3) << 3))
                                  : (((j >> 3) << 7) + (hh << 6) + ((j & 7) << 3));
            const u16* src = side ? Bm : A;
            const long rb  = side ? tileN : tileM;
            g2lds16(src + (size_t)(rb + prow + lrow) * (size_t)K + (size_t)(tt << 6) + scol,
                    &lds[bb][side][prow * 64]);
        }
    };

    short8 Af[4][2], Bf[4][2];
    auto quad = [&](int mb, int nb) {
#pragma unroll
        for (int m = 0; m < 4; ++m)
#pragma unroll
            for (int n = 0; n < 2; ++n) {
                acc[mb + m][nb + n] = __builtin_amdgcn_mfma_f32_16x16x32_bf16(
                    Af[m][0], Bf[nb + n][0], acc[mb + m][nb + n], 0, 0, 0);
                acc[mb + m][nb + n] = __builtin_amdgcn_mfma_f32_16x16x32_bf16(
                    Af[m][1], Bf[nb + n][1], acc[mb + m][nb + n], 0, 0, 0);
            }
    };

    // prologue: tile0 fully + tile1 {A-lo, B-hi, A-hi} (B-lo(1) staged at (0,ph0))
    stage(0, 0, 0, 0); stage(0, 1, 0, 0); stage(0, 1, 1, 0); stage(0, 0, 1, 0);
    stage(1, 0, 0, 1); stage(1, 1, 1, 1); stage(1, 0, 1, 1);
    asm volatile("s_waitcnt vmcnt(6)" ::: "memory");   // tile0 landed; tile1's 3 halves in flight
    __builtin_amdgcn_s_barrier();

    for (int t = 0; t < T; ++t) {
        const int cb = t & 1;
        const u16* lA = &lds[cb][0][0];
        const u16* lB = &lds[cb][1][0];

        // ---- phase 0: (m0-3, n0-1)
#pragma unroll
        for (int m = 0; m < 4; ++m) {
            const int ro = ((wr << 7) + (m << 4) + fr) * 64;
            Af[m][0] = *(const short8*)&lA[ro + kc0];
            Af[m][1] = *(const short8*)&lA[ro + kc1];
        }
#pragma unroll
        for (int n = 0; n < 2; ++n) {
            const int ro = ((wc << 6) + (n << 4) + fr) * 64;
            Bf[n][0] = *(const short8*)&lB[ro + kc0];
            Bf[n][1] = *(const short8*)&lB[ro + kc1];
        }
        if (t + 1 < T) stage(t + 1, 1, 0, cb ^ 1);
        asm volatile("" ::: "memory");
        __builtin_amdgcn_s_barrier();
        asm volatile("s_waitcnt lgkmcnt(0)" ::: "memory");
        __builtin_amdgcn_sched_barrier(0);
        __builtin_amdgcn_s_setprio(1);
        quad(0, 0);
        __builtin_amdgcn_s_setprio(0);
        asm volatile("" ::: "memory");
        __builtin_amdgcn_s_barrier();

        // ---- phase 1: (m0-3, n2-3)
#pragma unroll
        for (int n = 2; n < 4; ++n) {
            const int ro = ((wc << 6) + (n << 4) + fr) * 64;
            Bf[n][0] = *(const short8*)&lB[ro + kc0];
            Bf[n][1] = *(const short8*)&lB[ro + kc1];
        }
        if (t + 2 < T) stage(t + 2, 0, 0, cb);
        asm volatile("" ::: "memory");
        __builtin_amdgcn_s_barrier();
        asm volatile("s_waitcnt lgkmcnt(0)" ::: "memory");
        __builtin_amdgcn_sched_barrier(0);
        __builtin_amdgcn_s_setprio(1);
        quad(0, 2);
        __builtin_amdgcn_s_setprio(0);
        asm volatile("" ::: "memory");
        __builtin_amdgcn_s_barrier();

        // ---- phase 2: (m4-7, n2-3)
#pragma unroll
        for (int m = 0; m < 4; ++m) {
            const int ro = ((wr << 7) + ((m + 4) << 4) + fr) * 64;
            Af[m][0] = *(const short8*)&lA[ro + kc0];
            Af[m][1] = *(const short8*)&lA[ro + kc1];
        }
        if (t + 2 < T) stage(t + 2, 1, 1, cb);
        asm volatile("" ::: "memory");
        __builtin_amdgcn_s_barrier();
        asm volatile("s_waitcnt lgkmcnt(0)" ::: "memory");
        __builtin_amdgcn_sched_barrier(0);
        __builtin_amdgcn_s_setprio(1);
        quad(4, 2);
        __builtin_amdgcn_s_setprio(0);
        asm volatile("" ::: "memory");
        __builtin_amdgcn_s_barrier();

        // ---- phase 3: (m4-7, n0-1); no new ds_reads; tile-boundary vmcnt
        if (t + 2 < T) stage(t + 2, 0, 1, cb);
        asm volatile("" ::: "memory");
        __builtin_amdgcn_s_barrier();
        __builtin_amdgcn_s_setprio(1);
        quad(4, 0);
        __builtin_amdgcn_s_setprio(0);
        if (t + 1 < T) {
            if (t + 2 < T) asm volatile("s_waitcnt vmcnt(6)" ::: "memory");
            else           asm volatile("s_waitcnt vmcnt(0)" ::: "memory");
        }
        asm volatile("" ::: "memory");
        __builtin_amdgcn_s_barrier();
    }

    // ---- epilogue
#pragma unroll
    for (int j = 0; j < 4; ++j) {
        const long col = tileN + (wc << 6) + (j << 4) + fr;
        float bv = 0.f;
        if constexpr (BIAS) bv = bias[col];
#pragma unroll
        for (int i = 0; i < 8; ++i) {
            const long row0 = tileM + (wr << 7) + (i << 4) + (fq << 2);
#pragma unroll
            for (int r = 0; r < 4; ++r) {
                const float v = acc[i][j][r] + bv;
                const long row = row0 + r;
                if constexpr (OUT_FP32) {
                    ((float*)Cv + (long)bz * sC)[row * ldc + col] = v;
                } else if constexpr (TRANSC) {
                    const long b = row >> 10, mloc = row & 1023;
                    ((u16*)Cv)[b * sMDc + col * Mm + mloc] = f2bf(v);
                } else {
                    ((u16*)Cv + (long)bz * sC)[row * ldc + col] = f2bf(v);
                }
            }
        }
    }
}

// ---------------- fp32 -> bf16 conversion ----------------
__global__ __launch_bounds__(256) void conv_kernel(
    const float* __restrict__ src, u16* __restrict__ dst, size_t n8)
{
    const size_t stride = (size_t)gridDim.x * 256;
    for (size_t i = (size_t)blockIdx.x * 256 + threadIdx.x; i < n8; i += stride) {
        const float4 a = ((const float4*)src)[2 * i];
        const float4 b = ((const float4*)src)[2 * i + 1];
        short8 o;
        o[0]=(short)f2bf(a.x); o[1]=(short)f2bf(a.y); o[2]=(short)f2bf(a.z); o[3]=(short)f2bf(a.w);
        o[4]=(short)f2bf(b.x); o[5]=(short)f2bf(b.y); o[6]=(short)f2bf(b.z); o[7]=(short)f2bf(b.w);
        *(short8*)(dst + 8 * i) = o;
    }
}

// ---------------- 6x weight fp32 -> bf16 (one launch) ----------------
__global__ __launch_bounds__(256) void wconv6(
    const float* __restrict__ w0, const float* __restrict__ w1, const float* __restrict__ w2,
    const float* __restrict__ w3, const float* __restrict__ w4, const float* __restrict__ w5,
    u16* __restrict__ dst)
{
    const float* src;
    switch (blockIdx.y) {
        case 0: src = w0; break; case 1: src = w1; break; case 2: src = w2; break;
        case 3: src = w3; break; case 4: src = w4; break; default: src = w5; break;
    }
    const size_t i = (size_t)blockIdx.x * 256 + threadIdx.x;   // elem8 id, 131072 total
    const float4 a = ((const float4*)src)[2 * i];
    const float4 b = ((const float4*)src)[2 * i + 1];
    short8 o;
    o[0]=(short)f2bf(a.x); o[1]=(short)f2bf(a.y); o[2]=(short)f2bf(a.z); o[3]=(short)f2bf(a.w);
    o[4]=(short)f2bf(b.x); o[5]=(short)f2bf(b.y); o[6]=(short)f2bf(b.z); o[7]=(short)f2bf(b.w);
    *(short8*)(dst + (((size_t)blockIdx.y) << 20) + 8 * i) = o;
}

// ---------------- pooling ----------------
__global__ __launch_bounds__(256) void pool_kernel(
    const float* __restrict__ oV, const float* __restrict__ oT,
    float* __restrict__ vpool, float* __restrict__ tpool)
{
    const int col = blockIdx.x * 256 + threadIdx.x;
    const int b = blockIdx.y;
    const int src_i = blockIdx.z & 1, chunk = blockIdx.z >> 1;
    const float* src = (src_i ? oT : oV) + (size_t)b * Mm * Dd;
    const int r0 = chunk * (Mm / 4);
    float s = 0.f;
    for (int r = r0; r < r0 + Mm / 4; ++r) s += src[(size_t)r * Dd + col];
    float* dst = src_i ? tpool : vpool;
    atomicAdd(dst + b * Dd + col, s * (1.0f / Mm));
}

// ---------------- FFN ----------------
__global__ __launch_bounds__(256) void ffn1_kernel(
    const float* __restrict__ vpool, const float* __restrict__ tpool,
    const float* __restrict__ f1w, const float* __restrict__ f1b,
    float* __restrict__ hbuf)
{
    const int j = blockIdx.x, b = blockIdx.y;
    const int t = threadIdx.x, wv = t >> 6, lane = t & 63;
    __shared__ float red[4];
    const float* w = f1w + (size_t)j * (2 * Dd);
    float a = 0.f;
    for (int k = t; k < Dd; k += 256) a += vpool[b * Dd + k] * w[k];
    for (int k = t; k < Dd; k += 256) a += tpool[b * Dd + k] * w[Dd + k];
    a = waveSum(a);
    if (lane == 0) red[wv] = a;
    __syncthreads();
    if (t == 0) hbuf[b * HIDh + j] = fmaxf(red[0] + red[1] + red[2] + red[3] + f1b[j], 0.0f);
}

__global__ __launch_bounds__(256) void ffn2_kernel(
    const float* __restrict__ hbuf, const float* __restrict__ f2w,
    const float* __restrict__ f2b, float* __restrict__ lbuf)
{
    const int b = blockIdx.x;
    const int t = threadIdx.x, wv = t >> 6, lane = t & 63;
    __shared__ float red[4];
    float p = 0.f;
    for (int j = t; j < HIDh; j += 256) p += hbuf[b * HIDh + j] * f2w[j];
    p = waveSum(p);
    if (lane == 0) red[wv] = p;
    __syncthreads();
    if (t == 0) {
        const float z = red[0] + red[1] + red[2] + red[3] + f2b[0];
        lbuf[b] = 1.0f / (1.0f + expf(-z));
    }
}

// ---------------- sim softmax -> fp32 mask (d_out) ----------------
__global__ __launch_bounds__(256) void sim_softmax_mask(
    const u16* __restrict__ scores, const float* __restrict__ lbuf, float* __restrict__ maskF)
{
    const int row = blockIdx.x, b = blockIdx.y;
    const int t = threadIdx.x, wv = t >> 6, lane = t & 63;
    __shared__ float red[8];
    const size_t off = ((size_t)b * Mm + row) * Nn;
    const uint2 sv = *(const uint2*)(scores + off + 4 * t);
    const float x0 = bf2f((u16)(sv.x & 0xFFFFu)) * INV_SQRT_D;
    const float x1 = bf2f((u16)(sv.x >> 16))     * INV_SQRT_D;
    const float x2 = bf2f((u16)(sv.y & 0xFFFFu)) * INV_SQRT_D;
    const float x3 = bf2f((u16)(sv.y >> 16))     * INV_SQRT_D;
    float mx = waveMax(fmaxf(fmaxf(x0, x1), fmaxf(x2, x3)));
    if (lane == 0) red[wv] = mx;
    __syncthreads();
    mx = fmaxf(fmaxf(red[0], red[1]), fmaxf(red[2], red[3]));
    const float e0 = expf(x0 - mx), e1 = expf(x1 - mx), e2 = expf(x2 - mx), e3 = expf(x3 - mx);
    float s = waveSum(e0 + e1 + e2 + e3);
    if (lane == 0) red[4 + wv] = s;
    __syncthreads();
    const float inv = 1.0f / fmaxf(red[4] + red[5] + red[6] + red[7], 1e-30f);
    const float l = lbuf[b];
    float4 mk;
    mk.x = (e0 * inv >= l) ? 1.0f : 0.0f;
    mk.y = (e1 * inv >= l) ? 1.0f : 0.0f;
    mk.z = (e2 * inv >= l) ? 1.0f : 0.0f;
    mk.w = (e3 * inv >= l) ? 1.0f : 0.0f;
    *(float4*)(maskF + off + 4 * t) = mk;
}

// ---------------- mask transpose: fp32 mask[b][m][n] -> u8 maskT[b][n][m] ----------------
__global__ __launch_bounds__(256) void transpose_mask(
    const float* __restrict__ maskF, u8* __restrict__ maskT)
{
    __shared__ u8 tile[64][68];
    const int m0 = blockIdx.x * 64, n0 = blockIdx.y * 64, b = blockIdx.z;
    const int t = threadIdx.x;
    const int r = t >> 2, c = (t & 3) * 16;
    const float* src = maskF + ((size_t)b * Mm + (m0 + r)) * Nn + n0 + c;
    float4 f0 = ((const float4*)src)[0];
    float4 f1 = ((const float4*)src)[1];
    float4 f2 = ((const float4*)src)[2];
    float4 f3 = ((const float4*)src)[3];
    u8* dst = &tile[r][c];
    dst[0]=f0.x!=0.f; dst[1]=f0.y!=0.f; dst[2]=f0.z!=0.f; dst[3]=f0.w!=0.f;
    dst[4]=f1.x!=0.f; dst[5]=f1.y!=0.f; dst[6]=f1.z!=0.f; dst[7]=f1.w!=0.f;
    dst[8]=f2.x!=0.f; dst[9]=f2.y!=0.f; dst[10]=f2.z!=0.f; dst[11]=f2.w!=0.f;
    dst[12]=f3.x!=0.f; dst[13]=f3.y!=0.f; dst[14]=f3.z!=0.f; dst[15]=f3.w!=0.f;
    __syncthreads();
    union { u8 b[16]; uint4 v; } pk;
#pragma unroll
    for (int k = 0; k < 16; ++k) pk.b[k] = tile[c + k][r];
    *(uint4*)(maskT + ((size_t)b * Nn + (n0 + r)) * Mm + m0 + c) = pk.v;
}

// ---------------- masked softmax over bf16 scores, IN-PLACE -> bf16 attn ----------------
template <bool TRANSP>
__global__ __launch_bounds__(256) void masked_softmax(
    u16* __restrict__ scores, const float* __restrict__ maskF, const u8* __restrict__ maskT)
{
    const int row = blockIdx.x, b = blockIdx.y;
    const int t = threadIdx.x, wv = t >> 6, lane = t & 63;
    __shared__ float red[8];
    const size_t off = ((size_t)b * Mm + row) * Nn;
    const uint2 sv = *(const uint2*)(scores + off + 4 * t);
    float x0 = bf2f((u16)(sv.x & 0xFFFFu)) * INV_SQRT_D;
    float x1 = bf2f((u16)(sv.x >> 16))     * INV_SQRT_D;
    float x2 = bf2f((u16)(sv.y & 0xFFFFu)) * INV_SQRT_D;
    float x3 = bf2f((u16)(sv.y >> 16))     * INV_SQRT_D;
    if (TRANSP) {
        const u32 mk = *(const u32*)(maskT + off + 4 * t);
        if (!(mk & 0x000000FFu)) x0 = NEGINF;
        if (!(mk & 0x0000FF00u)) x1 = NEGINF;
        if (!(mk & 0x00FF0000u)) x2 = NEGINF;
        if (!(mk & 0xFF000000u)) x3 = NEGINF;
    } else {
        const float4 mk = *(const float4*)(maskF + off + 4 * t);
        if (mk.x == 0.f) x0 = NEGINF;
        if (mk.y == 0.f) x1 = NEGINF;
        if (mk.z == 0.f) x2 = NEGINF;
        if (mk.w == 0.f) x3 = NEGINF;
    }
    float mx = waveMax(fmaxf(fmaxf(x0, x1), fmaxf(x2, x3)));
    if (lane == 0) red[wv] = mx;
    __syncthreads();
    mx = fmaxf(fmaxf(red[0], red[1]), fmaxf(red[2], red[3]));
    const float e0 = expf(x0 - mx), e1 = expf(x1 - mx), e2 = expf(x2 - mx), e3 = expf(x3 - mx);
    float s = waveSum(e0 + e1 + e2 + e3);
    if (lane == 0) red[4 + wv] = s;
    __syncthreads();
    const float inv = 1.0f / fmaxf(red[4] + red[5] + red[6] + red[7], 1e-30f);
    uint2 pk;
    pk.x = (u32)f2bf(e0 * inv) | ((u32)f2bf(e1 * inv) << 16);
    pk.y = (u32)f2bf(e2 * inv) | ((u32)f2bf(e3 * inv) << 16);
    *(uint2*)(scores + off + 4 * t) = pk;
}

extern "C" void kernel_launch(void* const* d_in, const int* in_sizes, int n_in,
                              void* d_out, int out_size, void* d_ws, size_t ws_size,
                              hipStream_t stream)
{
    (void)in_sizes; (void)n_in; (void)out_size; (void)ws_size;
    const float* oV     = (const float*)d_in[0];
    const float* oT     = (const float*)d_in[1];
    const float* Wq_v_w = (const float*)d_in[2];
    const float* Wq_v_b = (const float*)d_in[3];
    const float* Wk_t_w = (const float*)d_in[4];
    const float* Wk_t_b = (const float*)d_in[5];
    const float* Wv_t_w = (const float*)d_in[6];
    const float* Wv_t_b = (const float*)d_in[7];
    const float* Wq_t_w = (const float*)d_in[8];
    const float* Wq_t_b = (const float*)d_in[9];
    const float* Wk_v_w = (const float*)d_in[10];
    const float* Wk_v_b = (const float*)d_in[11];
    const float* Wv_v_w = (const float*)d_in[12];
    const float* Wv_v_b = (const float*)d_in[13];
    const float* f1w    = (const float*)d_in[14];
    const float* f1b    = (const float*)d_in[15];
    const float* f2w    = (const float*)d_in[16];
    const float* f2b    = (const float*)d_in[17];

    float* out_vt = (float*)d_out;
    float* out_tv = out_vt + BMDc;
    float* maskF  = out_vt + 2 * BMDc;

    // workspace layout (~220 MB of 768 MB)
    u16* S0  = (u16*)d_ws;                       // Q projection        32 MB
    u16* S1  = S0 + BMDc;                        // K projection        32 MB
    u16* S2  = S1 + BMDc;                        // V^T projection      32 MB
    u16* S3  = S2 + BMDc;                        // scores/attn         32 MB
    u16* oVb = S3 + BMDc;                        // bf16 oV             32 MB
    u16* oTb = oVb + BMDc;                       // bf16 oT             32 MB
    u16* Wc  = oTb + BMDc;                       // 6x bf16 weights     12 MB
    u8*  maskT = (u8*)(Wc + 6 * (1 << 20));      // transposed u8 mask  16 MB
    float* vpool = (float*)(maskT + BMDc);
    float* tpool = vpool + Bz * Dd;
    float* hbuf  = tpool + Bz * Dd;
    float* lbuf  = hbuf + Bz * HIDh;

    const dim3 blk(256), blk512(512);
    const dim3 gBat(Mm / 256, Nn / 256, Bz);     // (4,4,16) = 256 wg
    const dim3 gProj(Bz * Mm / 256, Dd / 256, 1);// (64,4,1) = 256 wg
    const dim3 gRow(Mm, Bz);
    const dim3 gTrp(Mm / 64, Nn / 64, Bz);
    const long sMD = sMDc, sMN = (long)Mm * Nn;

    // 0: convert inputs + weights to bf16
    conv_kernel<<<dim3(4096), blk, 0, stream>>>(oV, oVb, BMDc / 8);
    conv_kernel<<<dim3(4096), blk, 0, stream>>>(oT, oTb, BMDc / 8);
    wconv6<<<dim3(512, 6), blk, 0, stream>>>(Wq_v_w, Wk_t_w, Wv_t_w, Wq_t_w, Wk_v_w, Wv_v_w, Wc);

    // 1-2: pools + threshold l
    hipMemsetAsync(vpool, 0, 2 * Bz * Dd * sizeof(float), stream);
    pool_kernel<<<dim3(Dd / 256, Bz, 8), blk, 0, stream>>>(oV, oT, vpool, tpool);
    ffn1_kernel<<<dim3(HIDh, Bz), blk, 0, stream>>>(vpool, tpool, f1w, f1b, hbuf);
    ffn2_kernel<<<dim3(Bz), blk, 0, stream>>>(hbuf, f2w, f2b, lbuf);

    // 3-4: sim scores -> mask (fp32 out) -> transposed u8 mask
    gemm256<false,false,false><<<gBat, blk512, 0, stream>>>(oVb, oTb, nullptr, S3, Dd, Nn, sMD, sMD, sMN);
    sim_softmax_mask<<<gRow, blk, 0, stream>>>(S3, lbuf, maskF);
    transpose_mask<<<gTrp, blk, 0, stream>>>(maskF, maskT);

    // 5-10: V->T.  Qv->S0, Kt->S1, Vt^T->S2.
    gemm256<false,true ,false><<<gProj, blk512, 0, stream>>>(oVb, Wc,                Wq_v_b, S0, Dd, Dd, 0, 0, 0);
    gemm256<false,true ,false><<<gProj, blk512, 0, stream>>>(oTb, Wc + (1 << 20),    Wk_t_b, S1, Dd, Dd, 0, 0, 0);
    gemm256<false,true ,true ><<<gProj, blk512, 0, stream>>>(oTb, Wc + 2 * (1 << 20),Wv_t_b, S2, Dd, Dd, 0, 0, 0);
    gemm256<false,false,false><<<gBat, blk512, 0, stream>>>(S0, S1, nullptr, S3, Dd, Nn, sMD, sMD, sMN);
    masked_softmax<false><<<gRow, blk, 0, stream>>>(S3, maskF, maskT);
    gemm256<true ,false,false><<<gBat, blk512, 0, stream>>>(S3, S2, nullptr, out_vt, Nn, Dd, sMN, sMD, sMD);

    // 11-16: T->V.  Qt->S0, Kv->S1, Vv^T->S2.
    gemm256<false,true ,false><<<gProj, blk512, 0, stream>>>(oTb, Wc + 3 * (1 << 20), Wq_t_b, S0, Dd, Dd, 0, 0, 0);
    gemm256<false,true ,false><<<gProj, blk512, 0, stream>>>(oVb, Wc + 4 * (1 << 20), Wk_v_b, S1, Dd, Dd, 0, 0, 0);
    gemm256<false,true ,true ><<<gProj, blk512, 0, stream>>>(oVb, Wc + 5 * (1 << 20), Wv_v_b, S2, Dd, Dd, 0, 0, 0);
    gemm256<false,false,false><<<gBat, blk512, 0, stream>>>(S0, S1, nullptr, S3, Dd, Nn, sMD, sMD, sMN);
    masked_softmax<true><<<gRow, blk, 0, stream>>>(S3, maskF, maskT);
    gemm256<true ,false,false><<<gBat, blk512, 0, stream>>>(S3, S2, nullptr, out_tv, Nn, Dd, sMN, sMD, sMD);
}